// Round 6
// baseline (105.235 us; speedup 1.0000x reference)
//
#include <hip/hip_runtime.h>
#include <hip/hip_bf16.h>

#define NOUT 7
#define NBIN 49
#define NCH 256

typedef unsigned short ushort8_t __attribute__((ext_vector_type(8)));

__device__ inline float bflo(unsigned int u) { return __uint_as_float(u << 16); }
__device__ inline float bfhi(unsigned int u) { return __uint_as_float(u & 0xffff0000u); }
__device__ inline unsigned short f2bf(float f) {
    __hip_bfloat16 h = __float2bfloat16(f);
    return *reinterpret_cast<unsigned short*>(&h);
}

// ---------- merged NCHW f32 -> NHWC bf16 transpose, 16B/lane both directions ----------
// per block: 64 p x 64 c. level block counts (nx * 4 ctiles * 2 batch):
// l0 950*8=7600, l1 238*8=1904, l2 60*8=480, l3 15*8=120 => 10104
__global__ __launch_bounds__(256) void transpose_all_kernel(
    const float* __restrict__ f0, const float* __restrict__ f1,
    const float* __restrict__ f2, const float* __restrict__ f3,
    unsigned short* __restrict__ ws)
{
    __shared__ float tile[64][68];   // [p][c], stride 68 dwords: 16B-aligned rows, +4 pad

    int bid = blockIdx.x;
    const float* in;
    unsigned short* out;
    int HW;
    if (bid < 7600)      { in = f0; out = ws;            HW = 60800; }
    else if (bid < 9504) { in = f1; out = ws + 31129600; HW = 15200; bid -= 7600; }
    else if (bid < 9984) { in = f2; out = ws + 38912000; HW = 3800;  bid -= 9504; }
    else                 { in = f3; out = ws + 40857600; HW = 950;   bid -= 9984; }

    const int nx  = (HW + 63) >> 6;
    const int p0  = (bid % nx) << 6;
    const int rem = bid / nx;
    const int c0  = (rem & 3) << 6;
    const int b   = rem >> 2;

    const int t  = threadIdx.x;
    const int pq = t & 15;        // p-quad within tile (p = pq*4..pq*4+3)
    const int ci = t >> 4;        // 0..15 channel index within pass

    const size_t inb = (size_t)b * NCH * (size_t)HW;
    #pragma unroll
    for (int pass = 0; pass < 4; ++pass) {
        const int c = pass * 16 + ci;             // 0..63 local channel
        const int p = pq * 4;                     // local p base
        const float* src = in + inb + (size_t)(c0 + c) * HW + (p0 + p);
        if (p0 + p + 3 < HW) {
            const float4 v = *(const float4*)src;
            tile[p + 0][c] = v.x;
            tile[p + 1][c] = v.y;
            tile[p + 2][c] = v.z;
            tile[p + 3][c] = v.w;
        } else {
            #pragma unroll
            for (int j = 0; j < 4; ++j)
                if (p0 + p + j < HW) tile[p + j][c] = src[j];
        }
    }
    __syncthreads();

    const size_t outb = (size_t)b * (size_t)HW * NCH;
    const int c8 = t & 7;         // 8-channel group
    const int pr = t >> 3;        // 0..31 p-row
    #pragma unroll
    for (int pass = 0; pass < 2; ++pass) {
        const int p = pass * 32 + pr;
        if (p0 + p < HW) {
            const float4 a = *(const float4*)&tile[p][c8 * 8];
            const float4 v = *(const float4*)&tile[p][c8 * 8 + 4];
            ushort8_t o;
            o[0] = f2bf(a.x); o[1] = f2bf(a.y); o[2] = f2bf(a.z); o[3] = f2bf(a.w);
            o[4] = f2bf(v.x); o[5] = f2bf(v.y); o[6] = f2bf(v.z); o[7] = f2bf(v.w);
            *(ushort8_t*)(out + outb + (size_t)(p0 + p) * NCH + (c0 + c8 * 8)) = o;
        }
    }
}

// ---------- pooling from NHWC bf16: wave-per-bin, 4 channels/lane (ushort4) ----------
__global__ __launch_bounds__(256) void pool_nhwc4_kernel(
    const unsigned short* __restrict__ ws, const float* __restrict__ boxes,
    const int* __restrict__ bidx, float* __restrict__ out, int nbox)
{
    __shared__ __align__(16) float so[NBIN * 260];   // [bin][channel], stride 260

    const int n = blockIdx.x;
    if (n >= nbox) return;
    const int lane = threadIdx.x & 63;
    const int wave = threadIdx.x >> 6;

    const float bx1 = boxes[4*n+0];
    const float by1 = boxes[4*n+1];
    const float bx2 = boxes[4*n+2];
    const float by2 = boxes[4*n+3];

    const float ww = bx2 - bx1 + 1.0f;
    const float hh = by2 - by1 + 1.0f;
    const float s  = sqrtf(ww * hh);
    int lvl = (int)floorf(4.0f + log2f(1e-6f + s * (1.0f / 224.0f)));
    lvl = min(max(lvl, 2), 5) - 2;

    int H, W;
    float scale;
    size_t off;
    if (lvl == 0)      { H = 200; W = 304; scale = 0.25f;    off = 0;        }
    else if (lvl == 1) { H = 100; W = 152; scale = 0.125f;   off = 31129600; }
    else if (lvl == 2) { H = 50;  W = 76;  scale = 0.0625f;  off = 38912000; }
    else               { H = 25;  W = 38;  scale = 0.03125f; off = 40857600; }

    const int b = bidx[n];
    const unsigned short* __restrict__ fb =
        ws + off + (size_t)b * (size_t)(H * W) * NCH + 4 * lane;

    const float x1 = bx1 * scale;
    const float y1 = by1 * scale;
    const float x2 = bx2 * scale;
    const float y2 = by2 * scale;
    const float roi_w = fmaxf(x2 - x1, 1.0f);
    const float roi_h = fmaxf(y2 - y1, 1.0f);
    const float bw = roi_w * (1.0f / NOUT);
    const float bh = roi_h * (1.0f / NOUT);

    const float Hf = (float)H, Wf = (float)W;

    for (int e = wave; e < NBIN; e += 4) {
        const int py = e / NOUT;
        const int px = e - py * NOUT;
        float a0 = 0.0f, a1 = 0.0f, a2 = 0.0f, a3 = 0.0f;
        #pragma unroll
        for (int iy = 0; iy < 2; ++iy) {
            #pragma unroll
            for (int ix = 0; ix < 2; ++ix) {
                float y = y1 + ((float)py + 0.25f + 0.5f * (float)iy) * bh;
                float x = x1 + ((float)px + 0.25f + 0.5f * (float)ix) * bw;
                const bool valid = (y >= -1.0f) && (y <= Hf) && (x >= -1.0f) && (x <= Wf);
                y = fminf(fmaxf(y, 0.0f), Hf - 1.0f);
                x = fminf(fmaxf(x, 0.0f), Wf - 1.0f);
                const int y0 = (int)floorf(y);
                const int x0 = (int)floorf(x);
                const int y1i = min(y0 + 1, H - 1);
                const int x1i = min(x0 + 1, W - 1);
                const float ly = y - (float)y0;
                const float lx = x - (float)x0;
                const float hy = 1.0f - ly;
                const float hx = 1.0f - lx;
                const float w00 = hy * hx, w01 = hy * lx, w10 = ly * hx, w11 = ly * lx;

                const uint2 u00 = *(const uint2*)(fb + (unsigned)(y0  * W + x0 ) * NCH);
                const uint2 u01 = *(const uint2*)(fb + (unsigned)(y0  * W + x1i) * NCH);
                const uint2 u10 = *(const uint2*)(fb + (unsigned)(y1i * W + x0 ) * NCH);
                const uint2 u11 = *(const uint2*)(fb + (unsigned)(y1i * W + x1i) * NCH);

                if (valid) {
                    a0 += w00 * bflo(u00.x) + w01 * bflo(u01.x) + w10 * bflo(u10.x) + w11 * bflo(u11.x);
                    a1 += w00 * bfhi(u00.x) + w01 * bfhi(u01.x) + w10 * bfhi(u10.x) + w11 * bfhi(u11.x);
                    a2 += w00 * bflo(u00.y) + w01 * bflo(u01.y) + w10 * bflo(u10.y) + w11 * bflo(u11.y);
                    a3 += w00 * bfhi(u00.y) + w01 * bfhi(u01.y) + w10 * bfhi(u10.y) + w11 * bfhi(u11.y);
                }
            }
        }
        float4 r;
        r.x = a0 * 0.25f; r.y = a1 * 0.25f; r.z = a2 * 0.25f; r.w = a3 * 0.25f;
        *(float4*)&so[e * 260 + 4 * lane] = r;
    }
    __syncthreads();

    // coalesced float4 write of this box's (256,7,7) block
    float* __restrict__ outn = out + (size_t)n * (NCH * NBIN);
    for (int idx = threadIdx.x; idx < (NCH * NBIN) / 4; idx += 256) {
        const int k = idx * 4;
        float4 r;
        {
            const int k0 = k;     const int c = k0 / NBIN; r.x = so[(k0 - c * NBIN) * 260 + c];
        }
        {
            const int k1 = k + 1; const int c = k1 / NBIN; r.y = so[(k1 - c * NBIN) * 260 + c];
        }
        {
            const int k2 = k + 2; const int c = k2 / NBIN; r.z = so[(k2 - c * NBIN) * 260 + c];
        }
        {
            const int k3 = k + 3; const int c = k3 / NBIN; r.w = so[(k3 - c * NBIN) * 260 + c];
        }
        ((float4*)outn)[idx] = r;
    }
}

// ---------------- fallback (round-1 kernel) if ws too small ----------------
__global__ __launch_bounds__(256) void pooler_kernel(
    const float* __restrict__ f0, const float* __restrict__ f1,
    const float* __restrict__ f2, const float* __restrict__ f3,
    const float* __restrict__ boxes, const int* __restrict__ bidx,
    float* __restrict__ out, int nbox)
{
    const int n = blockIdx.x;
    if (n >= nbox) return;
    const int c = threadIdx.x;

    const float bx1 = boxes[4*n+0];
    const float by1 = boxes[4*n+1];
    const float bx2 = boxes[4*n+2];
    const float by2 = boxes[4*n+3];

    const float ww = bx2 - bx1 + 1.0f;
    const float hh = by2 - by1 + 1.0f;
    const float s  = sqrtf(ww * hh);
    int lvl = (int)floorf(4.0f + log2f(1e-6f + s * (1.0f / 224.0f)));
    lvl = min(max(lvl, 2), 5) - 2;

    const float* f;
    int H, W;
    float scale;
    if (lvl == 0)      { f = f0; H = 200; W = 304; scale = 0.25f;    }
    else if (lvl == 1) { f = f1; H = 100; W = 152; scale = 0.125f;   }
    else if (lvl == 2) { f = f2; H = 50;  W = 76;  scale = 0.0625f;  }
    else               { f = f3; H = 25;  W = 38;  scale = 0.03125f; }

    const int b = bidx[n];
    const float* __restrict__ fb = f + ((size_t)b * NCH + c) * (size_t)(H * W);

    const float x1 = bx1 * scale;
    const float y1 = by1 * scale;
    const float x2 = bx2 * scale;
    const float y2 = by2 * scale;
    const float roi_w = fmaxf(x2 - x1, 1.0f);
    const float roi_h = fmaxf(y2 - y1, 1.0f);
    const float bw = roi_w * (1.0f / NOUT);
    const float bh = roi_h * (1.0f / NOUT);

    const float Hf = (float)H, Wf = (float)W;
    float* __restrict__ outc = out + ((size_t)n * NCH + c) * NBIN;

    for (int py = 0; py < NOUT; ++py) {
        for (int px = 0; px < NOUT; ++px) {
            float acc = 0.0f;
            #pragma unroll
            for (int iy = 0; iy < 2; ++iy) {
                #pragma unroll
                for (int ix = 0; ix < 2; ++ix) {
                    float y = y1 + ((float)py + 0.25f + 0.5f * (float)iy) * bh;
                    float x = x1 + ((float)px + 0.25f + 0.5f * (float)ix) * bw;
                    const bool valid = (y >= -1.0f) && (y <= Hf) && (x >= -1.0f) && (x <= Wf);
                    y = fminf(fmaxf(y, 0.0f), Hf - 1.0f);
                    x = fminf(fmaxf(x, 0.0f), Wf - 1.0f);
                    const int y0 = (int)floorf(y);
                    const int x0 = (int)floorf(x);
                    const int y1i = min(y0 + 1, H - 1);
                    const int x1i = min(x0 + 1, W - 1);
                    const float ly = y - (float)y0;
                    const float lx = x - (float)x0;
                    const float hy = 1.0f - ly;
                    const float hx = 1.0f - lx;
                    const float v00 = fb[y0  * W + x0 ];
                    const float v01 = fb[y0  * W + x1i];
                    const float v10 = fb[y1i * W + x0 ];
                    const float v11 = fb[y1i * W + x1i];
                    float v = hy * hx * v00 + hy * lx * v01
                            + ly * hx * v10 + ly * lx * v11;
                    acc += valid ? v : 0.0f;
                }
            }
            outc[py * NOUT + px] = acc * 0.25f;
        }
    }
}

extern "C" void kernel_launch(void* const* d_in, const int* in_sizes, int n_in,
                              void* d_out, int out_size, void* d_ws, size_t ws_size,
                              hipStream_t stream) {
    const float* f0    = (const float*)d_in[0];
    const float* f1    = (const float*)d_in[1];
    const float* f2    = (const float*)d_in[2];
    const float* f3    = (const float*)d_in[3];
    const float* boxes = (const float*)d_in[4];
    const int*   bidx  = (const int*)d_in[5];
    float*       out   = (float*)d_out;

    const int nbox = in_sizes[5];

    const size_t NEED = 41344000ull * sizeof(unsigned short);  // 82.7 MB
    if (ws_size >= NEED) {
        unsigned short* t = (unsigned short*)d_ws;
        transpose_all_kernel<<<10104, 256, 0, stream>>>(f0, f1, f2, f3, t);
        pool_nhwc4_kernel<<<nbox, 256, 0, stream>>>(t, boxes, bidx, out, nbox);
    } else {
        pooler_kernel<<<nbox, 256, 0, stream>>>(f0, f1, f2, f3, boxes, bidx, out, nbox);
    }
}